// Round 7
// baseline (254.543 us; speedup 1.0000x reference)
//
#include <hip/hip_runtime.h>
#include <math.h>

// Problem constants: y is (8, 3, 256, 512) fp32, lmbd is (1,3).
#define TVW 512      // row length
#define TVH 256      // H (for channel index)
#define TVC 3        // channels
#define WPB 2        // waves (= rows) per block; 3072 blocks -> 12 blk/CU, 24 waves/CU
#define BLOCK (WPB * 64)
#define RSTR 536     // per-row LDS stride: 512 + sentinel + 23 pad (2144B, 16B-aligned)
#define SENT -1.0e30f

// One wave per row. v10 = v9 (half-wave walk fusion, 12-deep 3-bank prefetch,
// literal/rcp reciprocals, half-split flushes, decoupled waves; 191us dispatch)
// + SENTINEL-TERMINATED UNBOUNDED LOOP. r2->r6 counters showed a constant
// ~86us of non-VALU time: per-phase bound checks, per-segment trips setup,
// remainder ladder, bank-exit selects. A -1e30 sentinel at xs[512] (both
// signed copies) makes the existing jump ballot fire at the row end on its
// own: the extend loop loses ALL bound checks; the fire path records the
// absorb index jk, and jk>=512 dispatches to the boundary handler (state at
// sentinel-fire == absorbed through W-1, exactly the old fallthrough state).
// Rows are stride-536 so ahead-reads stay inside the owning row. Decision
// sequence is bitwise-identical to v9.
__global__ __launch_bounds__(BLOCK)
void tv1d_condat_wave_kernel(const float* __restrict__ y,
                             const float* __restrict__ lmbd,
                             float* __restrict__ out,
                             int total_rows) {
    __shared__ __align__(16) float buf [WPB * RSTR];   // primary rows (output)
    __shared__ __align__(16) float bneg[WPB * RSTR];   // negated copy (read-only)
    const int tid  = threadIdx.x;
    const int wave = tid >> 6;
    const int lane = tid & 63;
    const int l32  = lane & 31;
    const bool hi  = lane >= 32;
    const int row  = blockIdx.x * WPB + wave;

    if (row < total_rows) {
        // ---- per-wave staging: own row + negated copy + sentinel/pads ----
        {
            const float4* s4 = (const float4*)(y + (size_t)row * TVW);
            float4* b4 = (float4*)(buf  + wave * RSTR);
            float4* n4 = (float4*)(bneg + wave * RSTR);
            #pragma unroll
            for (int i = 0; i < TVW / 4; i += 64) {
                const float4 vv = s4[i + lane];
                b4[i + lane] = vv;
                n4[i + lane] = make_float4(-vv.x, -vv.y, -vv.z, -vv.w);
            }
            if (lane < RSTR - TVW) {     // sentinel at [512], 0-pads after
                const float pv = (lane == 0) ? SENT : 0.0f;
                buf [wave * RSTR + TVW + lane] = pv;
                bneg[wave * RSTR + TVW + lane] = pv;
            }
        }

        const int c = (row / TVH) % TVC;
        float lam = log1pf(expf(lmbd[c]));   // softplus, once per row
        lam = __uint_as_float(__builtin_amdgcn_readfirstlane(__float_as_uint(lam)));
        const float nlam   = -lam;
        const float twolam = 2.0f * lam;
        float* x = buf + wave * RSTR;        // output row; prefix [..k0) never re-read
        const float* xs = hi ? (bneg + wave * RSTR) : (buf + wave * RSTR);
        const float cneg = hi ? twolam : 0.0f;  // v' = ownload - cneg after neg jump
        const float cpos = hi ? 0.0f : twolam;  // v' = ownload - cpos after pos jump

        // All cross-label state declared up-front (goto-safe).
        int k0, km, kp, kb, jk, seg_guard;
        unsigned long long jb;
        float u, v, nv, tt, wv, denf;
        float P0, P1, P2, P3, Q0, Q1, Q2, Q3, R0, R1, R2, R3;
        bool negj;

        // Packed walk state: lo lanes hold (umin,vmin); hi lanes hold (-umax,-vmax).
        k0 = 0; km = 0; kp = 0; jk = 0; seg_guard = 4096; jb = 0;
        v = xs[0] - lam;                 // lo: y0-lam ; hi: -(y0+lam)
        u = lam;
        P0 = xs[1];  P1 = xs[2];  P2 = xs[3];  P3 = xs[4];
        Q0 = xs[5];  Q1 = xs[6];  Q2 = xs[7];  Q3 = xs[8];
        R0 = xs[9];  R1 = xs[10]; R2 = xs[11]; R3 = xs[12];

// absorb one element: EV = xs[KC], RN = 1/den. Fire records jk = KC.
#define TVSTEP(EV, RN, KC) { \
            const float u_t = u + (EV) - v; \
            jb = __ballot(u_t < nlam);   /* lo: umin_t<-lam, hi: umax_t>lam */ \
            if (jb) { jk = (KC); goto midjump; } \
            const unsigned long long cb = __ballot(u_t >= lam); /* lo->km, hi->kp */ \
            const int kc_ = (KC); \
            km = (unsigned)(cb)       ? kc_ : km;   /* s_cselect */ \
            kp = (unsigned)(cb >> 32) ? kc_ : kp; \
            const float u_n = fminf(u_t, lam); \
            v = fmaf(u_t - u_n, (RN), v);  /* both clamp corrections */ \
            u = u_n; }

// steady phase: 4 absorbs off bank B (den = denf..denf+3), reload B 12 ahead
#define TVPHASE(B0_, B1_, B2_, B3_) { \
            TVSTEP(B0_, __builtin_amdgcn_rcpf(denf),        kb + 0) \
            TVSTEP(B1_, __builtin_amdgcn_rcpf(denf + 1.0f), kb + 1) \
            TVSTEP(B2_, __builtin_amdgcn_rcpf(denf + 2.0f), kb + 2) \
            TVSTEP(B3_, __builtin_amdgcn_rcpf(denf + 3.0f), kb + 3) \
            B0_ = xs[kb + 12]; B1_ = xs[kb + 13]; \
            B2_ = xs[kb + 14]; B3_ = xs[kb + 15]; \
            kb += 4; denf += 4.0f; }

seg_start:
        if (--seg_guard < 0) goto done;      // safety; k0 strictly increases
        // ---- peel: den 2..9, exact literal reciprocals (no bound checks) ----
        TVSTEP(P0, 0.5f,           k0 + 1)
        TVSTEP(P1, (1.0f / 3.0f),  k0 + 2)
        TVSTEP(P2, 0.25f,          k0 + 3)
        TVSTEP(P3, 0.2f,           k0 + 4)
        P0 = xs[k0 + 13]; P1 = xs[k0 + 14]; P2 = xs[k0 + 15]; P3 = xs[k0 + 16];
        TVSTEP(Q0, (1.0f / 6.0f),  k0 + 5)
        TVSTEP(Q1, (1.0f / 7.0f),  k0 + 6)
        TVSTEP(Q2, 0.125f,         k0 + 7)
        TVSTEP(Q3, (1.0f / 9.0f),  k0 + 8)
        Q0 = xs[k0 + 17]; Q1 = xs[k0 + 18]; Q2 = xs[k0 + 19]; Q3 = xs[k0 + 20];
        kb = k0 + 9; denf = 10.0f;
        // ---- unbounded steady loop (bank order R, P, Q); sentinel exits ----
        for (;;) {
            TVPHASE(R0, R1, R2, R3)
            TVPHASE(P0, P1, P2, P3)
            TVPHASE(Q0, Q1, Q2, Q3)
        }

midjump: // fire at absorb jk; jb lo bits = negative (priority), hi = positive
        if (jk >= TVW) goto boundary;        // sentinel: row-end handler
        {
            negj = (unsigned)jb != 0;
            const int fe = negj ? km : kp;   // flush end (scalar); fe <= W-2 here
            const int k0n = fe + 1;
            wv = hi ? -v : v;                // value this half would write
            nv = xs[k0n];                    // refill issued before the stores
            P0 = xs[k0n + 1];  P1 = xs[k0n + 2];  P2 = xs[k0n + 3];  P3 = xs[k0n + 4];
            Q0 = xs[k0n + 5];  Q1 = xs[k0n + 6];  Q2 = xs[k0n + 7];  Q3 = xs[k0n + 8];
            R0 = xs[k0n + 9];  R1 = xs[k0n + 10]; R2 = xs[k0n + 11]; R3 = xs[k0n + 12];
            // neg jump -> lo half writes vmin; pos jump -> hi half writes vmax
            if (negj != hi) {
                for (int p = k0 + l32; p <= fe; p += 32) x[p] = wv;
            }
            k0 = k0n; km = k0n; kp = k0n;
            v = nv - (negj ? cneg : cpos);   // lo/hi restart values (v9 algebra)
            u = lam;
            goto seg_start;
        }

boundary: // k == W-1 absorbed; u = umin (lo) / -umax (hi)
        {
            const unsigned long long bb = __ballot(u < 0.0f); // lo: umin<0, hi: umax>0
            if ((unsigned)bb) {              // flush [k0..km] at vmin; keep vmax/kp
                const int k0n = km + 1;
                wv = v;                      // lo lanes hold vmin natively
                if (k0n < TVW) {             // refill issued before the stores
                    nv = xs[k0n];
                    P0 = xs[k0n + 1];  P1 = xs[k0n + 2];  P2 = xs[k0n + 3];  P3 = xs[k0n + 4];
                    Q0 = xs[k0n + 5];  Q1 = xs[k0n + 6];  Q2 = xs[k0n + 7];  Q3 = xs[k0n + 8];
                    R0 = xs[k0n + 9];  R1 = xs[k0n + 10]; R2 = xs[k0n + 11]; R3 = xs[k0n + 12];
                }
                { const int pe = km < TVW - 1 ? km : TVW - 1;
                  if (!hi) for (int p = k0 + l32; p <= pe; p += 32) x[p] = wv; }
                if (k0n >= TVW) goto done;
                // lo: u'=lam, v'=nv ; hi: U'=(nv_hi-lam)-V_old, V'=V_old
                tt = nv - lam;
                u = hi ? (tt - v) : lam;
                v = hi ? v : nv;
                k0 = k0n; km = k0n;
                goto seg_start;
            } else if ((unsigned)(bb >> 32)) { // flush [k0..kp] at vmax; keep vmin/km
                const int k0n = kp + 1;
                wv = -v;                     // hi lanes hold -vmax natively
                if (k0n < TVW) {
                    nv = xs[k0n];
                    P0 = xs[k0n + 1];  P1 = xs[k0n + 2];  P2 = xs[k0n + 3];  P3 = xs[k0n + 4];
                    Q0 = xs[k0n + 5];  Q1 = xs[k0n + 6];  Q2 = xs[k0n + 7];  Q3 = xs[k0n + 8];
                    R0 = xs[k0n + 9];  R1 = xs[k0n + 10]; R2 = xs[k0n + 11]; R3 = xs[k0n + 12];
                }
                { const int pe = kp < TVW - 1 ? kp : TVW - 1;
                  if (hi) for (int p = k0 + l32; p <= pe; p += 32) x[p] = wv; }
                if (k0n >= TVW) goto done;
                // lo: u'=(nv_lo-lam)-vmin, v'=vmin ; hi: U'=lam, V'=nv_hi
                tt = nv - lam;
                u = hi ? lam : (tt - v);
                v = hi ? nv : v;
                k0 = k0n; kp = k0n;
                goto seg_start;
            } else {                         // terminate: flush tail at mean value
                const float vt = fmaf(u, __builtin_amdgcn_rcpf((float)(TVW - k0)), v);
                if (!hi) for (int p = k0 + l32; p < TVW; p += 32) x[p] = vt;
                goto done;
            }
        }
#undef TVPHASE
#undef TVSTEP
done:   ;
        // ---- per-wave coalesced float4 writeback LDS -> out ----
        {
            const float4* b4 = (const float4*)(buf + wave * RSTR);
            float4* d4 = (float4*)(out + (size_t)row * TVW);
            #pragma unroll
            for (int i = 0; i < TVW / 4; i += 64)
                d4[i + lane] = b4[i + lane];
        }
    }
}

extern "C" void kernel_launch(void* const* d_in, const int* in_sizes, int n_in,
                              void* d_out, int out_size, void* d_ws, size_t ws_size,
                              hipStream_t stream) {
    const float* y    = (const float*)d_in[0];
    const float* lmbd = (const float*)d_in[1];
    float* out = (float*)d_out;

    const int total_rows = in_sizes[0] / TVW;              // 6144
    const int grid = (total_rows + WPB - 1) / WPB;         // 3072 blocks
    tv1d_condat_wave_kernel<<<grid, BLOCK, 0, stream>>>(y, lmbd, out, total_rows);
}

// Round 8
// 237.963 us; speedup vs baseline: 1.0697x; 1.0697x over previous
//
#include <hip/hip_runtime.h>
#include <math.h>

// Problem constants: y is (8, 3, 256, 512) fp32, lmbd is (1,3).
#define TVW 512      // row length
#define TVH 256      // H (for channel index)
#define TVC 3        // channels
#define WPB 2        // waves (= rows) per block; 3072 blocks -> 12 blk/CU, 24 waves/CU
#define BLOCK (WPB * 64)
#define PAD 12       // ahead-load overrun room (max idx k0+t+16 <= 523 = TVW+11)
#define RTN 528      // reciprocal table size (max read index 524)

// One wave per row. v11 = v9 (half-wave walk fusion, 12-deep 3-bank y-prefetch,
// literal peel den 2..9, half-split flushes, decoupled waves; 191.8us dispatch)
// with the steady-phase v_rcp_f32 (quarter-rate transcendental, 4 per phase
// ~= 8 issue-cy per steady absorb) replaced by a PREFETCHED RECIPROCAL TABLE
// stream: rtab[i]=1/i in LDS, consumed as three float2-pair banks mirroring
// the y-banks, self-reloaded 12 absorbs ahead (same slack-8 schedule ->
// no new exposed latency). Per-segment initial banks are the constants
// rtab[10..21], loaded at seg_start under the peel's 8-step slack. All rtab
// reads are wave-uniform -> broadcast, no bank conflicts. rem/terminate keep
// rcp (cold). v10's sentinel flattening regressed (short segments pay full
// peel) -- v9's bounded skeleton restored verbatim.
__global__ __launch_bounds__(BLOCK)
void tv1d_condat_wave_kernel(const float* __restrict__ y,
                             const float* __restrict__ lmbd,
                             float* __restrict__ out,
                             int total_rows) {
    __shared__ __align__(16) float buf [WPB * TVW + PAD];   // primary rows (output)
    __shared__ __align__(16) float bneg[WPB * TVW + PAD];   // negated copy (read-only)
    __shared__ __align__(16) float rtab[RTN];               // 1/i table
    const int tid  = threadIdx.x;
    const int wave = tid >> 6;
    const int lane = tid & 63;
    const int l32  = lane & 31;
    const bool hi  = lane >= 32;
    const int row  = blockIdx.x * WPB + wave;

    // ---- per-wave staging: own row + negated copy (coalesced float4) ----
    if (row < total_rows) {
        const float4* s4 = (const float4*)(y + (size_t)row * TVW);
        float4* b4 = (float4*)(buf  + wave * TVW);
        float4* n4 = (float4*)(bneg + wave * TVW);
        #pragma unroll
        for (int i = 0; i < TVW / 4; i += 64) {
            const float4 vv = s4[i + lane];
            b4[i + lane] = vv;
            n4[i + lane] = make_float4(-vv.x, -vv.y, -vv.z, -vv.w);
        }
    }
    if (tid < PAD) {                     // pads: loaded into regs but never consumed
        buf [WPB * TVW + tid] = 0.0f;
        bneg[WPB * TVW + tid] = 0.0f;
    }
    for (int i = tid; i < RTN; i += BLOCK)
        rtab[i] = 1.0f / (float)(i == 0 ? 1 : i);
    __syncthreads();                     // start-only sync (rtab shared); end stays decoupled

    if (row < total_rows) {
        const int c = (row / TVH) % TVC;
        float lam = log1pf(expf(lmbd[c]));   // softplus, once per row
        lam = __uint_as_float(__builtin_amdgcn_readfirstlane(__float_as_uint(lam)));
        const float nlam   = -lam;
        const float twolam = 2.0f * lam;
        float* x = buf + wave * TVW;         // output row; prefix [..k0) never re-read
        const float* xs = hi ? (bneg + wave * TVW) : (buf + wave * TVW); // signed source
        const float cneg = hi ? twolam : 0.0f;  // v' = ownload - cneg after neg jump
        const float cpos = hi ? 0.0f : twolam;  // v' = ownload - cpos after pos jump

        // All cross-label state declared up-front (goto-safe).
        int k0, km, kp, t, trips, rem, seg_guard;
        unsigned long long jb;
        float u, v, nv, tt, wv, den_f;
        float P0, P1, P2, P3, Q0, Q1, Q2, Q3, R0, R1, R2, R3, e0, e1, e2;
        float2 TAr, TBr, TAp, TBp, TAq, TBq;     // reciprocal banks (r[den..den+3])
        const float* rt;                          // = rtab + (t+2) in steady loop
        bool negj;

        // Packed walk state: lo lanes hold (umin,vmin); hi lanes hold (-umax,-vmax).
        k0 = 0; km = 0; kp = 0; seg_guard = 2048; jb = 0;
        v = xs[0] - lam;                 // lo: y0-lam ; hi: -(y0+lam)
        u = lam;
        P0 = xs[1];  P1 = xs[2];  P2 = xs[3];  P3 = xs[4];
        Q0 = xs[5];  Q1 = xs[6];  Q2 = xs[7];  Q3 = xs[8];
        R0 = xs[9];  R1 = xs[10]; R2 = xs[11]; R3 = xs[12];

// absorb one element: EV = xs[KC], RN = 1/den for this step
#define TVSTEP(EV, RN, KC) { \
            const float u_t = u + (EV) - v; \
            jb = __ballot(u_t < nlam);   /* lo: umin_t<-lam, hi: umax_t>lam */ \
            if (jb) goto midjump; \
            const unsigned long long cb = __ballot(u_t >= lam); /* lo->km, hi->kp */ \
            const int kc_ = (KC); \
            km = (unsigned)(cb)       ? kc_ : km;   /* s_cselect */ \
            kp = (unsigned)(cb >> 32) ? kc_ : kp; \
            const float u_n = fminf(u_t, lam); \
            v = fmaf(u_t - u_n, (RN), v);  /* both clamp corrections */ \
            u = u_n; }

// steady phase: 4 absorbs off y-bank B with table bank TA/TB, then reload
// both 12 absorbs ahead (slack-8 schedule, same as v9)
#define TVPHASE(B0_, B1_, B2_, B3_, TA_, TB_) { \
            TVSTEP(B0_, TA_.x, k0 + t + 1) \
            TVSTEP(B1_, TA_.y, k0 + t + 2) \
            TVSTEP(B2_, TB_.x, k0 + t + 3) \
            TVSTEP(B3_, TB_.y, k0 + t + 4) \
            B0_ = xs[k0 + t + 13]; B1_ = xs[k0 + t + 14]; \
            B2_ = xs[k0 + t + 15]; B3_ = xs[k0 + t + 16]; \
            TA_ = *(const float2*)(rt + 12); \
            TB_ = *(const float2*)(rt + 14); \
            rt += 4; t += 4; }

seg_start:
        if (--seg_guard < 0) goto done;      // safety; k0 strictly increases
        trips = (TVW - 1) - k0;
        // table banks for den 10..21: constant addresses, 8-step peel slack
        TAr = *(const float2*)(rtab + 10); TBr = *(const float2*)(rtab + 12);
        TAp = *(const float2*)(rtab + 14); TBp = *(const float2*)(rtab + 16);
        TAq = *(const float2*)(rtab + 18); TBq = *(const float2*)(rtab + 20);
        if (trips < 4) { t = 0; e0 = P0; e1 = P1; e2 = P2; goto rem_steps; }
        // ---- peel block 0 (t=0..3), exact literal reciprocals ----
        TVSTEP(P0, 0.5f,           k0 + 1)
        TVSTEP(P1, (1.0f / 3.0f),  k0 + 2)
        TVSTEP(P2, 0.25f,          k0 + 3)
        TVSTEP(P3, 0.2f,           k0 + 4)
        P0 = xs[k0 + 13]; P1 = xs[k0 + 14]; P2 = xs[k0 + 15]; P3 = xs[k0 + 16];
        if (trips < 8) { t = 4; e0 = Q0; e1 = Q1; e2 = Q2; goto rem_steps; }
        // ---- peel block 1 (t=4..7) ----
        TVSTEP(Q0, (1.0f / 6.0f),  k0 + 5)
        TVSTEP(Q1, (1.0f / 7.0f),  k0 + 6)
        TVSTEP(Q2, 0.125f,         k0 + 7)
        TVSTEP(Q3, (1.0f / 9.0f),  k0 + 8)
        Q0 = xs[k0 + 17]; Q1 = xs[k0 + 18]; Q2 = xs[k0 + 19]; Q3 = xs[k0 + 20];
        t = 8;
        rt = rtab + 10;                      // = rtab + t + 2
        // ---- steady three-phase loop (bank order R, P, Q); table-fed ----
        for (;;) {
            if (t + 4 > trips) { e0 = R0; e1 = R1; e2 = R2; break; }
            TVPHASE(R0, R1, R2, R3, TAr, TBr)
            if (t + 4 > trips) { e0 = P0; e1 = P1; e2 = P2; break; }
            TVPHASE(P0, P1, P2, P3, TAp, TBp)
            if (t + 4 > trips) { e0 = Q0; e1 = Q1; e2 = Q2; break; }
            TVPHASE(Q0, Q1, Q2, Q3, TAq, TBq)
        }
rem_steps:
        rem = trips - t;                     // 0..3
        if (rem > 0) {
            den_f = (float)(t + 2);
            TVSTEP(e0, __builtin_amdgcn_rcpf(den_f), k0 + t + 1)
            if (rem > 1) {
                TVSTEP(e1, __builtin_amdgcn_rcpf(den_f + 1.0f), k0 + t + 2)
                if (rem > 2) {
                    TVSTEP(e2, __builtin_amdgcn_rcpf(den_f + 2.0f), k0 + t + 3)
                }
            }
        }

        // ---- boundary: k == W-1, den = trips+1 ----
        {
            const unsigned long long bb = __ballot(u < 0.0f); // lo: umin<0, hi: umax>0
            if ((unsigned)bb) {              // flush [k0..km] at vmin; keep vmax/kp
                const int k0n = km + 1;
                wv = v;                      // lo lanes hold vmin natively
                if (k0n < TVW) {             // refill issued before the stores
                    nv = xs[k0n];
                    P0 = xs[k0n + 1];  P1 = xs[k0n + 2];  P2 = xs[k0n + 3];  P3 = xs[k0n + 4];
                    Q0 = xs[k0n + 5];  Q1 = xs[k0n + 6];  Q2 = xs[k0n + 7];  Q3 = xs[k0n + 8];
                    R0 = xs[k0n + 9];  R1 = xs[k0n + 10]; R2 = xs[k0n + 11]; R3 = xs[k0n + 12];
                }
                { const int pe = km < TVW - 1 ? km : TVW - 1;
                  if (!hi) for (int p = k0 + l32; p <= pe; p += 32) x[p] = wv; }
                if (k0n >= TVW) goto done;
                // lo: u'=lam, v'=nv ; hi: U'=(nv_hi-lam)-V_old, V'=V_old
                tt = nv - lam;
                u = hi ? (tt - v) : lam;
                v = hi ? v : nv;
                k0 = k0n; km = k0n;
                goto seg_start;
            } else if ((unsigned)(bb >> 32)) { // flush [k0..kp] at vmax; keep vmin/km
                const int k0n = kp + 1;
                wv = -v;                     // hi lanes hold -vmax natively
                if (k0n < TVW) {
                    nv = xs[k0n];
                    P0 = xs[k0n + 1];  P1 = xs[k0n + 2];  P2 = xs[k0n + 3];  P3 = xs[k0n + 4];
                    Q0 = xs[k0n + 5];  Q1 = xs[k0n + 6];  Q2 = xs[k0n + 7];  Q3 = xs[k0n + 8];
                    R0 = xs[k0n + 9];  R1 = xs[k0n + 10]; R2 = xs[k0n + 11]; R3 = xs[k0n + 12];
                }
                { const int pe = kp < TVW - 1 ? kp : TVW - 1;
                  if (hi) for (int p = k0 + l32; p <= pe; p += 32) x[p] = wv; }
                if (k0n >= TVW) goto done;
                // lo: u'=(nv_lo-lam)-vmin, v'=vmin ; hi: U'=lam, V'=nv_hi
                tt = nv - lam;
                u = hi ? lam : (tt - v);
                v = hi ? nv : v;
                k0 = k0n; kp = k0n;
                goto seg_start;
            } else {                         // terminate: flush tail at mean value
                const float vt = fmaf(u, __builtin_amdgcn_rcpf((float)(trips + 1)), v);
                if (!hi) for (int p = k0 + l32; p < TVW; p += 32) x[p] = vt;
                goto done;
            }
        }

midjump: // jump while absorbing; jb lo bits = negative (priority), hi = positive
        {
            negj = (unsigned)jb != 0;
            const int fe = negj ? km : kp;   // flush end (scalar); fe <= W-2 here
            const int k0n = fe + 1;
            wv = hi ? -v : v;                // value this half would write
            nv = xs[k0n];                    // refill issued before the stores
            P0 = xs[k0n + 1];  P1 = xs[k0n + 2];  P2 = xs[k0n + 3];  P3 = xs[k0n + 4];
            Q0 = xs[k0n + 5];  Q1 = xs[k0n + 6];  Q2 = xs[k0n + 7];  Q3 = xs[k0n + 8];
            R0 = xs[k0n + 9];  R1 = xs[k0n + 10]; R2 = xs[k0n + 11]; R3 = xs[k0n + 12];
            // neg jump -> lo half writes vmin; pos jump -> hi half writes vmax
            if (negj != hi) {
                for (int p = k0 + l32; p <= fe; p += 32) x[p] = wv;
            }
            k0 = k0n; km = k0n; kp = k0n;
            v = nv - (negj ? cneg : cpos);   // lo/hi restart values (v9 algebra)
            u = lam;
            goto seg_start;
        }
#undef TVPHASE
#undef TVSTEP
done:   ;
        // ---- per-wave coalesced float4 writeback LDS -> out ----
        {
            const float4* b4 = (const float4*)(buf + wave * TVW);
            float4* d4 = (float4*)(out + (size_t)row * TVW);
            #pragma unroll
            for (int i = 0; i < TVW / 4; i += 64)
                d4[i + lane] = b4[i + lane];
        }
    }
}

extern "C" void kernel_launch(void* const* d_in, const int* in_sizes, int n_in,
                              void* d_out, int out_size, void* d_ws, size_t ws_size,
                              hipStream_t stream) {
    const float* y    = (const float*)d_in[0];
    const float* lmbd = (const float*)d_in[1];
    float* out = (float*)d_out;

    const int total_rows = in_sizes[0] / TVW;              // 6144
    const int grid = (total_rows + WPB - 1) / WPB;         // 3072 blocks
    tv1d_condat_wave_kernel<<<grid, BLOCK, 0, stream>>>(y, lmbd, out, total_rows);
}

// Round 10
// 236.552 us; speedup vs baseline: 1.0761x; 1.0060x over previous
//
#include <hip/hip_runtime.h>
#include <math.h>

// Problem constants: y is (8, 3, 256, 512) fp32, lmbd is (1,3).
#define TVW 512      // row length
#define TVH 256      // H (for channel index)
#define TVC 3        // channels
#define WPB 2        // waves (= rows) per block; 3072 blocks -> 12 blk/CU, 24 waves/CU
#define BLOCK (WPB * 64)
#define PAD 12       // ahead-load overrun room (max idx k0+t+16 <= 523 = TVW+11)
#define RTN 528      // reciprocal table size (max read index 524)

// RESUBMISSION of v12 (round-9 bench died with "container failed twice" --
// infra failure, no measurement; source audited, no hang/OOB found).
//
// One wave per row. v12 = v11 (half-wave walk fusion, 12-deep 3-bank y-prefetch,
// rtab reciprocal stream, literal peel, half-split flushes; 190us dispatch)
// + SALU OFFLOAD. The CU has ONE scalar unit shared by 4 SIMDs; per-absorb
// audit: VALU ~4 CU-cy vs SALU ~7-9 CU-cy (clamp-index cselects, mask tests,
// kc adds) -> VALUBusy pinned at ~53% because the SHARED SCALAR PIPE is the
// bottleneck. Fix: move per-step scalar machinery to vector pipes:
//  - km/kp tracked per-lane in a VGPR (kmv): lo lanes' clamp hit IS the km
//    condition, hi lanes' IS kp -> one v_cmp + v_cndmask replaces the 2nd
//    ballot + ~4 SALU/step. Per-lane counter kcv replaces scalar kc adds.
//  - handlers recover the flush end with one v_readlane (lane 0 = km,
//    lane 32 = kp); boundary resets are half-selective cndmasks.
//  - midjump flush fast-path: scalar-guarded single predicated store.
// Decision sequence identical to v11/v9.
__global__ __launch_bounds__(BLOCK)
void tv1d_condat_wave_kernel(const float* __restrict__ y,
                             const float* __restrict__ lmbd,
                             float* __restrict__ out,
                             int total_rows) {
    __shared__ __align__(16) float buf [WPB * TVW + PAD];   // primary rows (output)
    __shared__ __align__(16) float bneg[WPB * TVW + PAD];   // negated copy (read-only)
    __shared__ __align__(16) float rtab[RTN];               // 1/i table
    const int tid  = threadIdx.x;
    const int wave = tid >> 6;
    const int lane = tid & 63;
    const int l32  = lane & 31;
    const bool hi  = lane >= 32;
    const int row  = blockIdx.x * WPB + wave;

    // ---- per-wave staging: own row + negated copy (coalesced float4) ----
    if (row < total_rows) {
        const float4* s4 = (const float4*)(y + (size_t)row * TVW);
        float4* b4 = (float4*)(buf  + wave * TVW);
        float4* n4 = (float4*)(bneg + wave * TVW);
        #pragma unroll
        for (int i = 0; i < TVW / 4; i += 64) {
            const float4 vv = s4[i + lane];
            b4[i + lane] = vv;
            n4[i + lane] = make_float4(-vv.x, -vv.y, -vv.z, -vv.w);
        }
    }
    if (tid < PAD) {                     // pads: loaded into regs but never consumed
        buf [WPB * TVW + tid] = 0.0f;
        bneg[WPB * TVW + tid] = 0.0f;
    }
    for (int i = tid; i < RTN; i += BLOCK)
        rtab[i] = 1.0f / (float)(i == 0 ? 1 : i);
    __syncthreads();                     // start-only sync; end stays decoupled

    if (row < total_rows) {
        const int c = (row / TVH) % TVC;
        float lam = log1pf(expf(lmbd[c]));   // softplus, once per row
        lam = __uint_as_float(__builtin_amdgcn_readfirstlane(__float_as_uint(lam)));
        const float nlam   = -lam;
        const float twolam = 2.0f * lam;
        float* x = buf + wave * TVW;         // output row; prefix [..k0) never re-read
        const float* xs = hi ? (bneg + wave * TVW) : (buf + wave * TVW); // signed source
        const float cneg = hi ? twolam : 0.0f;  // v' = ownload - cneg after neg jump
        const float cpos = hi ? 0.0f : twolam;  // v' = ownload - cpos after pos jump

        // All cross-label state declared up-front (goto-safe).
        int k0, t, trips, rem, seg_guard;
        int kmv, kcv;                        // PER-LANE: lo = km-track, hi = kp-track
        unsigned long long jb;
        float u, v, nv, tt, wv, den_f;
        float P0, P1, P2, P3, Q0, Q1, Q2, Q3, R0, R1, R2, R3, e0, e1, e2;
        float2 TAr, TBr, TAp, TBp, TAq, TBq;     // reciprocal banks
        const float* rt;                          // = rtab + (t+2) in steady loop
        bool negj;

        // Packed walk state: lo lanes hold (umin,vmin); hi lanes hold (-umax,-vmax).
        k0 = 0; seg_guard = 2048; jb = 0;
        kmv = 0; kcv = 1;                    // clamp-index track / absorb counter
        v = xs[0] - lam;                 // lo: y0-lam ; hi: -(y0+lam)
        u = lam;
        P0 = xs[1];  P1 = xs[2];  P2 = xs[3];  P3 = xs[4];
        Q0 = xs[5];  Q1 = xs[6];  Q2 = xs[7];  Q3 = xs[8];
        R0 = xs[9];  R1 = xs[10]; R2 = xs[11]; R3 = xs[12];

// absorb one element: EV = xs value, RN = 1/den. All tracking vector-side.
#define TVSTEP(EV, RN) { \
            const float u_t = u + (EV) - v; \
            jb = __ballot(u_t < nlam);   /* lo: umin_t<-lam, hi: umax_t>lam */ \
            if (jb) goto midjump; \
            kmv = (u_t >= lam) ? kcv : kmv;  /* v_cmp + v_cndmask (lo:km, hi:kp) */ \
            kcv += 1; \
            const float u_n = fminf(u_t, lam); \
            v = fmaf(u_t - u_n, (RN), v);  /* both clamp corrections */ \
            u = u_n; }

// steady phase: 4 absorbs off y-bank B with table bank TA/TB, reload 12 ahead
#define TVPHASE(B0_, B1_, B2_, B3_, TA_, TB_) { \
            TVSTEP(B0_, TA_.x) \
            TVSTEP(B1_, TA_.y) \
            TVSTEP(B2_, TB_.x) \
            TVSTEP(B3_, TB_.y) \
            B0_ = xs[k0 + t + 13]; B1_ = xs[k0 + t + 14]; \
            B2_ = xs[k0 + t + 15]; B3_ = xs[k0 + t + 16]; \
            TA_ = *(const float2*)(rt + 12); \
            TB_ = *(const float2*)(rt + 14); \
            rt += 4; t += 4; }

seg_start:
        if (--seg_guard < 0) goto done;      // safety; k0 strictly increases
        trips = (TVW - 1) - k0;
        // table banks for den 10..21: constant addresses, 8-step peel slack
        TAr = *(const float2*)(rtab + 10); TBr = *(const float2*)(rtab + 12);
        TAp = *(const float2*)(rtab + 14); TBp = *(const float2*)(rtab + 16);
        TAq = *(const float2*)(rtab + 18); TBq = *(const float2*)(rtab + 20);
        if (trips < 4) { t = 0; e0 = P0; e1 = P1; e2 = P2; goto rem_steps; }
        // ---- peel block 0 (t=0..3), exact literal reciprocals ----
        TVSTEP(P0, 0.5f)
        TVSTEP(P1, (1.0f / 3.0f))
        TVSTEP(P2, 0.25f)
        TVSTEP(P3, 0.2f)
        P0 = xs[k0 + 13]; P1 = xs[k0 + 14]; P2 = xs[k0 + 15]; P3 = xs[k0 + 16];
        if (trips < 8) { t = 4; e0 = Q0; e1 = Q1; e2 = Q2; goto rem_steps; }
        // ---- peel block 1 (t=4..7) ----
        TVSTEP(Q0, (1.0f / 6.0f))
        TVSTEP(Q1, (1.0f / 7.0f))
        TVSTEP(Q2, 0.125f)
        TVSTEP(Q3, (1.0f / 9.0f))
        Q0 = xs[k0 + 17]; Q1 = xs[k0 + 18]; Q2 = xs[k0 + 19]; Q3 = xs[k0 + 20];
        t = 8;
        rt = rtab + 10;                      // = rtab + t + 2
        // ---- steady three-phase loop (bank order R, P, Q); table-fed ----
        for (;;) {
            if (t + 4 > trips) { e0 = R0; e1 = R1; e2 = R2; break; }
            TVPHASE(R0, R1, R2, R3, TAr, TBr)
            if (t + 4 > trips) { e0 = P0; e1 = P1; e2 = P2; break; }
            TVPHASE(P0, P1, P2, P3, TAp, TBp)
            if (t + 4 > trips) { e0 = Q0; e1 = Q1; e2 = Q2; break; }
            TVPHASE(Q0, Q1, Q2, Q3, TAq, TBq)
        }
rem_steps:
        rem = trips - t;                     // 0..3
        if (rem > 0) {
            den_f = (float)(t + 2);
            TVSTEP(e0, __builtin_amdgcn_rcpf(den_f))
            if (rem > 1) {
                TVSTEP(e1, __builtin_amdgcn_rcpf(den_f + 1.0f))
                if (rem > 2) {
                    TVSTEP(e2, __builtin_amdgcn_rcpf(den_f + 2.0f))
                }
            }
        }

        // ---- boundary: k == W-1, den = trips+1 ----
        {
            const unsigned long long bb = __ballot(u < 0.0f); // lo: umin<0, hi: umax>0
            if ((unsigned)bb) {              // flush [k0..km] at vmin; keep vmax/kp
                const int fe = __builtin_amdgcn_readlane(kmv, 0);   // km
                const int k0n = fe + 1;
                wv = v;                      // lo lanes hold vmin natively
                if (k0n < TVW) {             // refill issued before the stores
                    nv = xs[k0n];
                    P0 = xs[k0n + 1];  P1 = xs[k0n + 2];  P2 = xs[k0n + 3];  P3 = xs[k0n + 4];
                    Q0 = xs[k0n + 5];  Q1 = xs[k0n + 6];  Q2 = xs[k0n + 7];  Q3 = xs[k0n + 8];
                    R0 = xs[k0n + 9];  R1 = xs[k0n + 10]; R2 = xs[k0n + 11]; R3 = xs[k0n + 12];
                }
                { const int pe = fe < TVW - 1 ? fe : TVW - 1;
                  if (!hi) for (int p = k0 + l32; p <= pe; p += 32) x[p] = wv; }
                if (k0n >= TVW) goto done;
                // lo: u'=lam, v'=nv ; hi: U'=(nv_hi-lam)-V_old, V'=V_old
                tt = nv - lam;
                u = hi ? (tt - v) : lam;
                v = hi ? v : nv;
                k0 = k0n;
                kmv = hi ? kmv : k0n;        // reset km (lo) only; kp kept
                kcv = k0n + 1;
                goto seg_start;
            } else if ((unsigned)(bb >> 32)) { // flush [k0..kp] at vmax; keep vmin/km
                const int fe = __builtin_amdgcn_readlane(kmv, 32);  // kp
                const int k0n = fe + 1;
                wv = -v;                     // hi lanes hold -vmax natively
                if (k0n < TVW) {
                    nv = xs[k0n];
                    P0 = xs[k0n + 1];  P1 = xs[k0n + 2];  P2 = xs[k0n + 3];  P3 = xs[k0n + 4];
                    Q0 = xs[k0n + 5];  Q1 = xs[k0n + 6];  Q2 = xs[k0n + 7];  Q3 = xs[k0n + 8];
                    R0 = xs[k0n + 9];  R1 = xs[k0n + 10]; R2 = xs[k0n + 11]; R3 = xs[k0n + 12];
                }
                { const int pe = fe < TVW - 1 ? fe : TVW - 1;
                  if (hi) for (int p = k0 + l32; p <= pe; p += 32) x[p] = wv; }
                if (k0n >= TVW) goto done;
                // lo: u'=(nv_lo-lam)-vmin, v'=vmin ; hi: U'=lam, V'=nv_hi
                tt = nv - lam;
                u = hi ? lam : (tt - v);
                v = hi ? nv : v;
                k0 = k0n;
                kmv = hi ? k0n : kmv;        // reset kp (hi) only; km kept
                kcv = k0n + 1;
                goto seg_start;
            } else {                         // terminate: flush tail at mean value
                const float vt = fmaf(u, __builtin_amdgcn_rcpf((float)(trips + 1)), v);
                if (!hi) for (int p = k0 + l32; p < TVW; p += 32) x[p] = vt;
                goto done;
            }
        }

midjump: // jump while absorbing; jb lo bits = negative (priority), hi = positive
        {
            negj = (unsigned)jb != 0;
            const int fe = __builtin_amdgcn_readlane(kmv, negj ? 0 : 32); // km or kp
            const int k0n = fe + 1;          // fe <= W-2 here
            wv = hi ? -v : v;                // value this half would write
            nv = xs[k0n];                    // refill issued before the stores
            P0 = xs[k0n + 1];  P1 = xs[k0n + 2];  P2 = xs[k0n + 3];  P3 = xs[k0n + 4];
            Q0 = xs[k0n + 5];  Q1 = xs[k0n + 6];  Q2 = xs[k0n + 7];  Q3 = xs[k0n + 8];
            R0 = xs[k0n + 9];  R1 = xs[k0n + 10]; R2 = xs[k0n + 11]; R3 = xs[k0n + 12];
            // neg jump -> lo half writes vmin; pos jump -> hi half writes vmax
            {
                const int p0 = k0 + l32;
                if ((negj != hi) && (p0 <= fe)) x[p0] = wv;   // common case: 1 store
                if (fe - k0 >= 32) {                          // rare long segment
                    if (negj != hi)
                        for (int p = p0 + 32; p <= fe; p += 32) x[p] = wv;
                }
            }
            k0 = k0n;
            kmv = k0n; kcv = k0n + 1;        // reset both tracks
            v = nv - (negj ? cneg : cpos);   // lo/hi restart values (v9 algebra)
            u = lam;
            goto seg_start;
        }
#undef TVPHASE
#undef TVSTEP
done:   ;
        // ---- per-wave coalesced float4 writeback LDS -> out ----
        {
            const float4* b4 = (const float4*)(buf + wave * TVW);
            float4* d4 = (float4*)(out + (size_t)row * TVW);
            #pragma unroll
            for (int i = 0; i < TVW / 4; i += 64)
                d4[i + lane] = b4[i + lane];
        }
    }
}

extern "C" void kernel_launch(void* const* d_in, const int* in_sizes, int n_in,
                              void* d_out, int out_size, void* d_ws, size_t ws_size,
                              hipStream_t stream) {
    const float* y    = (const float*)d_in[0];
    const float* lmbd = (const float*)d_in[1];
    float* out = (float*)d_out;

    const int total_rows = in_sizes[0] / TVW;              // 6144
    const int grid = (total_rows + WPB - 1) / WPB;         // 3072 blocks
    tv1d_condat_wave_kernel<<<grid, BLOCK, 0, stream>>>(y, lmbd, out, total_rows);
}